// Round 2
// baseline (244.708 us; speedup 1.0000x reference)
//
#include <hip/hip_runtime.h>
#include <math.h>

// Problem: B=4, H=16, N=4096, D=128 -> ROWS = B*H = 64 independent scan rows.
static constexpr int ROWS = 64;
static constexpr int NSEQ = 4096;
static constexpr int DIM  = 128;
static constexpr int TCH  = 32;           // chunk length (timesteps)
static constexpr int CPR  = NSEQ / TCH;   // chunks per row = 128
static constexpr int NCH  = ROWS * CPR;   // 8192 chunks total
static constexpr int GPB  = 8;            // 32-lane groups (=chunks) per 256-thread block
static constexpr int U    = 8;            // timestep unroll (ILP batch)

// ---------------------------------------------------------------------------
// K1: per 32-lane group, one chunk of 32 timesteps.
// Batched: load 8 steps of q/k/v up front, 8 independent shfl-reduce trees,
// then the (cheap) serial scalar rescale chain. Stores alphas + aggregates.
// ---------------------------------------------------------------------------
__global__ __launch_bounds__(256, 4) void fla_k1(
    const float* __restrict__ q, const float* __restrict__ k,
    const float* __restrict__ v,
    float* __restrict__ wsAlpha, float* __restrict__ aggM,
    float* __restrict__ aggD, float* __restrict__ aggN)
{
    const int lane = threadIdx.x & 31;
    const int g    = blockIdx.x * GPB + (threadIdx.x >> 5);   // global chunk id
    const int base = g * (TCH * DIM);                         // fits in int (33.5M max)

    float m_cur = -INFINITY;
    float d_run = 0.0f;
    float4 acc  = make_float4(0.f, 0.f, 0.f, 0.f);
    float aKeep = 0.f;   // lane l keeps alpha for t==l (TCH==32)

    for (int t0 = 0; t0 < TCH; t0 += U) {
        float4 q4[U], k4[U], v4[U];
        float  p[U];
        #pragma unroll
        for (int u = 0; u < U; ++u) {
            q4[u] = *((const float4*)(q + base + (t0 + u) * DIM) + lane);
            k4[u] = *((const float4*)(k + base + (t0 + u) * DIM) + lane);
        }
        #pragma unroll
        for (int u = 0; u < U; ++u)
            v4[u] = *((const float4*)(v + base + (t0 + u) * DIM) + lane);
        #pragma unroll
        for (int u = 0; u < U; ++u)
            p[u] = q4[u].x * k4[u].x + q4[u].y * k4[u].y
                 + q4[u].z * k4[u].z + q4[u].w * k4[u].w;
        // 8 independent butterfly trees (masks <=16 stay in the 32-lane half)
        #pragma unroll
        for (int m = 16; m >= 1; m >>= 1) {
            #pragma unroll
            for (int u = 0; u < U; ++u) p[u] += __shfl_xor(p[u], m);
        }
        // serial scalar chain: ~4 dependent VALU ops per step, negligible
        #pragma unroll
        for (int u = 0; u < U; ++u) {
            const int t = t0 + u;
            aKeep = (t == lane) ? p[u] : aKeep;
            const float m_new = fmaxf(m_cur, p[u]);
            const float f = __expf(m_cur - m_new);   // exp(-inf)=0 on first step
            const float w = __expf(p[u] - m_new);
            d_run = d_run * f + w;
            acc.x = acc.x * f + w * v4[u].x;
            acc.y = acc.y * f + w * v4[u].y;
            acc.z = acc.z * f + w * v4[u].z;
            acc.w = acc.w * f + w * v4[u].w;
            m_cur = m_new;
        }
    }

    wsAlpha[g * TCH + lane] = aKeep;                 // coalesced, 1 dword/lane
    if (lane == 0) { aggM[g] = m_cur; aggD[g] = d_run; }
    *((float4*)(aggN + g * DIM) + lane) = acc;       // lane owns dims [4l,4l+4)
}

// ---------------------------------------------------------------------------
// K2: per row, sequential scan over CPR chunk aggregates. Converts the
// aggregate arrays IN PLACE into EXCLUSIVE prefixes. Barrier between the
// cross-thread read of aggM/aggD and thread-0's overwrite keeps it race-free.
// ---------------------------------------------------------------------------
__global__ __launch_bounds__(128) void fla_k2(
    float* __restrict__ aggM, float* __restrict__ aggD, float* __restrict__ aggN)
{
    const int r = blockIdx.x;
    const int d = threadIdx.x;
    float m = -INFINITY, dd = 0.f, n = 0.f;
    for (int c = 0; c < CPR; ++c) {
        const int g = r * CPR + c;
        const float Mc = aggM[g];            // read by all 128 threads
        const float Dc = aggD[g];
        const float nc = aggN[g * DIM + d];  // read/write same thread -> safe
        __syncthreads();                     // all reads done before overwrite
        if (d == 0) { aggM[g] = m; aggD[g] = dd; }
        aggN[g * DIM + d] = n;
        const float mn = fmaxf(m, Mc);
        const float f1 = __expf(m - mn);     // 0 when m=-inf
        const float f2 = __expf(Mc - mn);
        dd = dd * f1 + Dc * f2;
        n  = n  * f1 + nc * f2;
        m  = mn;
    }
}

// ---------------------------------------------------------------------------
// K3: per 32-lane group, replay one chunk seeded with the exclusive prefix;
// v prefetched 8 steps at a time; alphas shfl-broadcast from one register.
// ---------------------------------------------------------------------------
__global__ __launch_bounds__(256, 4) void fla_k3(
    const float* __restrict__ v, const float* __restrict__ wsAlpha,
    const float* __restrict__ preM, const float* __restrict__ preD,
    const float* __restrict__ preN, float* __restrict__ y)
{
    const int lane = threadIdx.x & 31;
    const int g    = blockIdx.x * GPB + (threadIdx.x >> 5);
    const int base = g * (TCH * DIM);

    const float a0 = wsAlpha[g * TCH + lane];
    float m_cur = preM[g];               // uniform across group
    float d_run = preD[g];
    float4 acc  = *((const float4*)(preN + g * DIM) + lane);

    for (int t0 = 0; t0 < TCH; t0 += U) {
        float4 v4[U];
        #pragma unroll
        for (int u = 0; u < U; ++u)
            v4[u] = *((const float4*)(v + base + (t0 + u) * DIM) + lane);
        #pragma unroll
        for (int u = 0; u < U; ++u) {
            const float s = __shfl(a0, t0 + u, 32);
            const float m_new = fmaxf(m_cur, s);
            const float f = __expf(m_cur - m_new);
            const float w = __expf(s - m_new);
            d_run = d_run * f + w;
            acc.x = acc.x * f + w * v4[u].x;
            acc.y = acc.y * f + w * v4[u].y;
            acc.z = acc.z * f + w * v4[u].z;
            acc.w = acc.w * f + w * v4[u].w;
            const float rinv = __builtin_amdgcn_rcpf(d_run);
            float4 y4;
            y4.x = acc.x * rinv;
            y4.y = acc.y * rinv;
            y4.z = acc.z * rinv;
            y4.w = acc.w * rinv;
            *((float4*)(y + base + (t0 + u) * DIM) + lane) = y4;
            m_cur = m_new;
        }
    }
}

// ---------------------------------------------------------------------------
extern "C" void kernel_launch(void* const* d_in, const int* in_sizes, int n_in,
                              void* d_out, int out_size, void* d_ws, size_t ws_size,
                              hipStream_t stream) {
    const float* q = (const float*)d_in[0];
    const float* k = (const float*)d_in[1];
    const float* v = (const float*)d_in[2];
    float* y  = (float*)d_out;
    float* ws = (float*)d_ws;

    // ws layout (floats): alpha | aggM | aggD | aggN   (in-place -> prefixes)
    float* wsAlpha = ws;                          // ROWS*NSEQ = 262144
    float* aggM    = wsAlpha + ROWS * NSEQ;       // NCH = 8192
    float* aggD    = aggM + NCH;                  // NCH
    float* aggN    = aggD + NCH;                  // NCH*DIM = 1048576
    // total: 1,327,104 floats = 5.31 MB (same footprint as round 1)

    fla_k1<<<NCH / GPB, 256, 0, stream>>>(q, k, v, wsAlpha, aggM, aggD, aggN);
    fla_k2<<<ROWS, DIM, 0, stream>>>(aggM, aggD, aggN);
    fla_k3<<<NCH / GPB, 256, 0, stream>>>(v, wsAlpha, aggM, aggD, aggN, y);
}

// Round 3
// 177.527 us; speedup vs baseline: 1.3784x; 1.3784x over previous
//
#include <hip/hip_runtime.h>
#include <math.h>

// B=4, H=16, N=4096, D=128 -> 64 independent scan rows of length 4096.
static constexpr int ROWS = 64;
static constexpr int NSEQ = 4096;
static constexpr int DIM  = 128;
static constexpr int SC   = 32;              // scalar sub-chunk length
static constexpr int SPR  = NSEQ / SC;       // 128 sub-chunks per row
static constexpr int NSC  = ROWS * SPR;      // 8192 sub-chunks
static constexpr int VC   = 64;              // vector chunk length
static constexpr int VPR  = NSEQ / VC;       // 64 chunks per row
static constexpr int NVC  = ROWS * VPR;      // 4096 vector chunks

// ---------------------------------------------------------------------------
// k_alpha: alpha_t = dot(q_t,k_t); per sub-chunk max M and local denom D.
// 32-lane group per sub-chunk, U=4 ILP, small live state (no big arrays).
// ---------------------------------------------------------------------------
__global__ __launch_bounds__(256) void k_alpha(
    const float* __restrict__ q, const float* __restrict__ k,
    float* __restrict__ alpha, float* __restrict__ cM, float* __restrict__ cD)
{
    const int lane = threadIdx.x & 31;
    const int s    = blockIdx.x * 8 + (threadIdx.x >> 5);   // sub-chunk id
    const int base = s * (SC * DIM);

    float aKeep = 0.f;          // lane l keeps alpha for t==l
    float mRun  = -INFINITY;    // running max over the sub-chunk (all lanes)

    for (int t0 = 0; t0 < SC; t0 += 4) {
        float p[4];
        #pragma unroll
        for (int u = 0; u < 4; ++u) {
            const float4 a = *((const float4*)(q + base + (t0 + u) * DIM) + lane);
            const float4 b = *((const float4*)(k + base + (t0 + u) * DIM) + lane);
            p[u] = a.x * b.x + a.y * b.y + a.z * b.z + a.w * b.w;
        }
        #pragma unroll
        for (int m = 16; m >= 1; m >>= 1) {
            #pragma unroll
            for (int u = 0; u < 4; ++u) p[u] += __shfl_xor(p[u], m);
        }
        #pragma unroll
        for (int u = 0; u < 4; ++u) {
            aKeep = (t0 + u == lane) ? p[u] : aKeep;
            mRun  = fmaxf(mRun, p[u]);
        }
    }
    alpha[s * SC + lane] = aKeep;                   // coalesced
    // local denom: sum over lanes of exp(alpha_l - M)
    float e = __expf(aKeep - mRun);
    #pragma unroll
    for (int m = 16; m >= 1; m >>= 1) e += __shfl_xor(e, m);
    if (lane == 0) { cM[s] = mRun; cD[s] = e; }
}

// ---------------------------------------------------------------------------
// k_scan: per row (64 blocks):
//  A) stage cM/cD into LDS
//  1) thread-0 serial exclusive scan over 128 sub-chunks -> pM,pD
//  2) per-sub-chunk coefficient chains -> coefCW[t] = (c_t, w_t) global coeffs
// ---------------------------------------------------------------------------
__global__ __launch_bounds__(256) void k_scan(
    const float* __restrict__ alpha, const float* __restrict__ cM,
    const float* __restrict__ cD,
    float* __restrict__ pM, float* __restrict__ pD, float2* __restrict__ coefCW)
{
    __shared__ float lM[SPR], lD[SPR], lpM[SPR], lpD[SPR];
    const int row  = blockIdx.x;
    const int lane = threadIdx.x & 31;
    const int g    = threadIdx.x >> 5;     // 0..7

    // phase A: stage sub-chunk aggregates
    if (threadIdx.x < SPR) {
        lM[threadIdx.x] = cM[row * SPR + threadIdx.x];
        lD[threadIdx.x] = cD[row * SPR + threadIdx.x];
    }
    __syncthreads();

    // phase 1: serial scalar exclusive scan (128 steps, LDS-resident)
    if (threadIdx.x == 0) {
        float m = -INFINITY, d = 0.f;
        for (int sl = 0; sl < SPR; ++sl) {
            lpM[sl] = m; lpD[sl] = d;
            pM[row * SPR + sl] = m; pD[row * SPR + sl] = d;
            const float M = lM[sl], D = lD[sl];
            const float mn = fmaxf(m, M);
            d = d * __expf(m - mn) + D * __expf(M - mn);
            m = mn;
        }
    }
    __syncthreads();

    // phase 2: per-sub-chunk chains producing global per-timestep (c_t, w_t)
    for (int sl = g; sl < SPR; sl += 8) {
        const int s = row * SPR + sl;
        const float a = alpha[s * SC + lane];
        float m = lpM[sl];
        float cK = 0.f, wK = 0.f;
        for (int t = 0; t < SC; ++t) {
            const float at = __shfl(a, t, 32);
            const float mn = fmaxf(m, at);
            const float c  = __expf(m - mn);     // exp(-inf)=0 on first step
            const float w  = __expf(at - mn);
            cK = (t == lane) ? c : cK;
            wK = (t == lane) ? w : wK;
            m = mn;
        }
        coefCW[s * SC + lane] = make_float2(cK, wK);
    }
}

// ---------------------------------------------------------------------------
// k_agg: per vector chunk (one wave, lane owns 2 dims): n'_C via the global
// coefficient recurrence seeded 0. Result is normalized at the chunk-end
// global max (pM[2C+2]) so the prefix combine factor is exp(pM[2C]-pM[2C+2]).
// ---------------------------------------------------------------------------
__global__ __launch_bounds__(256) void k_agg(
    const float* __restrict__ v, const float2* __restrict__ coefCW,
    float2* __restrict__ aggN)
{
    const int lane  = threadIdx.x & 63;
    const int C     = blockIdx.x * 4 + (threadIdx.x >> 6);
    const int vbase = C * (VC * DIM);
    const int cbase = __builtin_amdgcn_readfirstlane(C * VC);

    float nx = 0.f, ny = 0.f;
    for (int t0 = 0; t0 < VC; t0 += 8) {
        float2 cw[8], vv[8];
        #pragma unroll
        for (int u = 0; u < 8; ++u) cw[u] = coefCW[cbase + t0 + u];
        #pragma unroll
        for (int u = 0; u < 8; ++u)
            vv[u] = *((const float2*)(v + vbase + (t0 + u) * DIM) + lane);
        #pragma unroll
        for (int u = 0; u < 8; ++u) {
            nx = cw[u].x * nx + cw[u].y * vv[u].x;
            ny = cw[u].x * ny + cw[u].y * vv[u].y;
        }
    }
    aggN[C * (DIM / 2) + lane] = make_float2(nx, ny);
}

// ---------------------------------------------------------------------------
// k_pref: per row, exclusive prefix scan of aggN over 64 chunks (in place),
// combine factor f1 = exp(pM[2C] - pM[2C+2]). Prefetch 8 ahead.
// ---------------------------------------------------------------------------
__global__ __launch_bounds__(128) void k_pref(
    float* __restrict__ aggN, const float* __restrict__ pM)
{
    const int row = blockIdx.x;
    const int d   = threadIdx.x;
    float state = 0.f;
    for (int C0 = 0; C0 < VPR; C0 += 8) {
        float nb[8], f1[8];
        #pragma unroll
        for (int u = 0; u < 8; ++u) {
            const int C = C0 + u;
            nb[u] = aggN[(row * VPR + C) * DIM + d];
            const int Cg = row * VPR + C;
            const float mp  = pM[2 * Cg];
            const bool last = (C == VPR - 1);
            const float mp2 = last ? 0.f : pM[2 * Cg + 2];
            f1[u] = last ? 0.f : __expf(mp - mp2);
        }
        #pragma unroll
        for (int u = 0; u < 8; ++u) {
            const float nc = nb[u];
            aggN[(row * VPR + C0 + u) * DIM + d] = state;
            state = state * f1[u] + nc;
        }
    }
}

// ---------------------------------------------------------------------------
// k_out: per vector chunk (one wave, lane owns 2 dims): replay the global
// recurrence seeded with the exclusive prefixes; y_t = n_t * rcp(d_t).
// ---------------------------------------------------------------------------
__global__ __launch_bounds__(256) void k_out(
    const float* __restrict__ v, const float2* __restrict__ coefCW,
    const float2* __restrict__ preN, const float* __restrict__ pD,
    float* __restrict__ y)
{
    const int lane  = threadIdx.x & 63;
    const int C     = blockIdx.x * 4 + (threadIdx.x >> 6);
    const int vbase = C * (VC * DIM);
    const int cbase = __builtin_amdgcn_readfirstlane(C * VC);

    float2 n  = preN[C * (DIM / 2) + lane];
    float dch = pD[2 * C];

    for (int t0 = 0; t0 < VC; t0 += 8) {
        float2 cw[8], vv[8];
        #pragma unroll
        for (int u = 0; u < 8; ++u) cw[u] = coefCW[cbase + t0 + u];
        #pragma unroll
        for (int u = 0; u < 8; ++u)
            vv[u] = *((const float2*)(v + vbase + (t0 + u) * DIM) + lane);
        #pragma unroll
        for (int u = 0; u < 8; ++u) {
            n.x = cw[u].x * n.x + cw[u].y * vv[u].x;
            n.y = cw[u].x * n.y + cw[u].y * vv[u].y;
            dch = cw[u].x * dch + cw[u].y;
            const float rd = __builtin_amdgcn_rcpf(dch);
            *((float2*)(y + vbase + (t0 + u) * DIM) + lane) =
                make_float2(n.x * rd, n.y * rd);
        }
    }
}

// ---------------------------------------------------------------------------
extern "C" void kernel_launch(void* const* d_in, const int* in_sizes, int n_in,
                              void* d_out, int out_size, void* d_ws, size_t ws_size,
                              hipStream_t stream) {
    const float* q = (const float*)d_in[0];
    const float* k = (const float*)d_in[1];
    const float* v = (const float*)d_in[2];
    float* y  = (float*)d_out;
    float* ws = (float*)d_ws;

    // ws layout (floats):
    //  coefCW : 524288   (float2[262144], global per-timestep (c,w))
    //  pM,pD  : 8192 each (exclusive scalar prefixes at sub-chunk grain)
    //  cM,cD  : 8192 each (sub-chunk local max / denom)
    //  U      : 524288   (alpha uses first 262144; aggN reuses all of it)
    float*  coefCWf = ws;
    float*  pM      = coefCWf + 2 * ROWS * NSEQ;       // 524288
    float*  pD      = pM + NSC;
    float*  cM      = pD + NSC;
    float*  cD      = cM + NSC;
    float*  U       = cD + NSC;                        // union region
    float*  alphaA  = U;                               // 262144 floats
    float*  aggNf   = U;                               // 524288 floats (after k_scan)
    float2* coefCW  = (float2*)coefCWf;
    float2* aggN2   = (float2*)aggNf;
    // total: 1,081,344 floats = 4.33 MB (< proven 5.31 MB)

    k_alpha<<<NSC / 8, 256, 0, stream>>>(q, k, alphaA, cM, cD);
    k_scan<<<ROWS, 256, 0, stream>>>(alphaA, cM, cD, pM, pD, coefCW);
    k_agg<<<NVC / 4, 256, 0, stream>>>(v, coefCW, aggN2);
    k_pref<<<ROWS, DIM, 0, stream>>>(aggNf, pM);
    k_out<<<NVC / 4, 256, 0, stream>>>(v, coefCW, aggN2, pD, y);
}